// Round 17
// baseline (165.940 us; speedup 1.0000x reference)
//
#include <hip/hip_runtime.h>
#include <hip/hip_bf16.h>

// Types
typedef short  bf16x8 __attribute__((ext_vector_type(8)));
typedef float  f32x4  __attribute__((ext_vector_type(4)));
typedef unsigned int uint4v __attribute__((ext_vector_type(4)));
typedef unsigned long u64x2 __attribute__((ext_vector_type(2)));
typedef unsigned short ushort_t;

#define GLD_LDS16(gp, lp) __builtin_amdgcn_global_load_lds(                 \
    (const __attribute__((address_space(1))) void*)(gp),                    \
    (__attribute__((address_space(3))) void*)(lp), 16, 0, 0)

static __device__ inline short f2bf(float x) {
    unsigned u = __builtin_bit_cast(unsigned, x);
    u += 0x7fffu + ((u >> 16) & 1u);
    return (short)(u >> 16);
}

// ---------------------------------------------------------------------------
// Pre-pass: feats f32 -> fp8 e4m3, PAIR-INTERLEAVED row-major (R16, verified
// absmax 0.0). Unit g of K-tile kt: bytes[0:8)=frag(ks=0,g), [8:16)=frag(ks=1,g).
// One ds_read_b128 at (row, g*16) yields BOTH K=32 fragments.
// ---------------------------------------------------------------------------
__global__ __launch_bounds__(256)
void convert_pair8_kernel(const float* __restrict__ in,
                          unsigned char* __restrict__ out,
                          int N, int D)
{
    int uid = blockIdx.x * blockDim.x + threadIdx.x;   // 16B unit id
    int nw  = D >> 4;                                  // units per row
    if (uid >= N * nw) return;
    int row = uid / nw;
    int w   = uid - row * nw;
    int kt  = w >> 2;
    int g   = w & 3;
    int k0  = kt * 64 + g * 8;
    const float* s = in + (size_t)row * D + k0;
    f32x4 a0 = *(const f32x4*)s;
    f32x4 a1 = *(const f32x4*)(s + 4);
    f32x4 b0 = *(const f32x4*)(s + 32);
    f32x4 b1 = *(const f32x4*)(s + 36);
    unsigned w0 = __builtin_amdgcn_cvt_pk_fp8_f32(a0[0], a0[1], 0, 0);
    w0 = __builtin_amdgcn_cvt_pk_fp8_f32(a0[2], a0[3], w0, 1);
    unsigned w1 = __builtin_amdgcn_cvt_pk_fp8_f32(a1[0], a1[1], 0, 0);
    w1 = __builtin_amdgcn_cvt_pk_fp8_f32(a1[2], a1[3], w1, 1);
    unsigned w2 = __builtin_amdgcn_cvt_pk_fp8_f32(b0[0], b0[1], 0, 0);
    w2 = __builtin_amdgcn_cvt_pk_fp8_f32(b0[2], b0[3], w2, 1);
    unsigned w3 = __builtin_amdgcn_cvt_pk_fp8_f32(b1[0], b1[1], 0, 0);
    w3 = __builtin_amdgcn_cvt_pk_fp8_f32(b1[2], b1[3], w3, 1);
    uint4v v = {w0, w1, w2, w3};
    *(uint4v*)(out + (size_t)uid * 16) = v;
}

// ---------------------------------------------------------------------------
// Gram kernel: TRIANGLE grid (T=528, 2.06 queued/CU), 128x128 tile, 256
// threads (4 waves 2x2, 64x64 each, acc[4][4]), K-tile=64 pair-interleaved
// fp8, ONE phase per K-tile (8 ds_read_b128 + 32 MFMA/wave), 3-slot 48KB
// LDS rotation -> 3 blocks/CU co-resident: cross-block overlap hides the
// per-phase barrier/latency bubbles (m114 mechanism) that the 1-block/CU
// 256x256 template exposed. Counted-vmcnt discipline identical to
// R14/R16 (verified): stage kt+2 at kt, retire kt+1's 4 loads at kt's
// boundary via vmcnt(4), kt+2's stay in flight; tail vmcnt(0).
// accbuf: [0]=S0 [1]=S1 [2]=ps [3]=pc
// ---------------------------------------------------------------------------
__global__ __launch_bounds__(256, 3)
void gram_tri8_kernel(const unsigned char* __restrict__ fb,
                      const int* __restrict__ labels,
                      const int* __restrict__ biases,
                      float* __restrict__ accbuf,
                      int N, int D)
{
    __shared__ unsigned char As[3][128][64];   // 24KB
    __shared__ unsigned char Bs[3][128][64];   // 24KB
    __shared__ int lab_r[128], bia_r[128], lab_c[128], bia_c[128];

    // XCD-aware bijective swizzle (528 % 8 == 0)
    int t = blockIdx.x;
    int nwg = gridDim.x;
    if ((nwg & 7) == 0) t = (t & 7) * (nwg >> 3) + (t >> 3);

    // tile -> lower-triangular (r >= c)  [R2-verified mapping]
    int r = (int)((sqrtf(8.0f * (float)t + 1.0f) - 1.0f) * 0.5f);
    while ((r + 1) * (r + 2) / 2 <= t) ++r;
    while (r * (r + 1) / 2 > t) --r;
    int c = t - r * (r + 1) / 2;
    int rowbase = r * 128, colbase = c * 128;

    int tid = threadIdx.x;
    if (tid < 128) {
        lab_r[tid] = labels[rowbase + tid];
        bia_r[tid] = biases[rowbase + tid];
    } else {
        int u = tid - 128;
        lab_c[u] = labels[colbase + u];
        bia_c[u] = biases[colbase + u];
    }

    int lane = tid & 63;
    int wid  = tid >> 6;               // 4 waves
    int wr   = wid >> 1;               // 2x2 wave grid, 64x64 each
    int wc   = wid & 1;
    int lrow = lane & 15;
    int kgrp = lane >> 4;

    // stage one tile (128 rows x 64B = 8KB = 512 x 16B): 2 gloads/thread.
    auto STAGE_A = [&](int slot, int kt) {
        #pragma unroll
        for (int i = 0; i < 2; ++i) {
            int j   = i * 256 + tid;           // 0..511
            int row = j >> 2;
            int blk = j & 3;
            const unsigned char* g =
                fb + (size_t)(rowbase + row) * D + kt * 64 + blk * 16;
            GLD_LDS16(g, &As[slot][0][0] + j * 16);
        }
    };
    auto STAGE_B = [&](int slot, int kt) {
        #pragma unroll
        for (int i = 0; i < 2; ++i) {
            int j   = i * 256 + tid;
            int row = j >> 2;
            int blk = j & 3;
            const unsigned char* g =
                fb + (size_t)(colbase + row) * D + kt * 64 + blk * 16;
            GLD_LDS16(g, &Bs[slot][0][0] + j * 16);
        }
    };

    f32x4 acc[4][4] = {};
    int nkt = D >> 6;                  // 32 K-tiles

    // ---- prologue: kt0 -> slot0 (4 loads/thr), kt1 -> slot1 (4);
    //      retire kt0's, keep kt1's in flight ----
    STAGE_A(0, 0); STAGE_B(0, 0);
    STAGE_A(1, 1); STAGE_B(1, 1);
    asm volatile("s_waitcnt vmcnt(4)" ::: "memory");
    __builtin_amdgcn_s_barrier();

    int slot = 0, s2 = 2;              // s2 = (kt+2)%3
    for (int kt = 0; kt < nkt; ++kt) {
        int stg = (kt + 2 < nkt);

        // ---- ds_read fragments from slot[kt%3] (b128 paired) ----
        u64x2 a[4], b[4];
        #pragma unroll
        for (int m = 0; m < 4; ++m) {
            int lr = wr * 64 + m * 16 + lrow;
            a[m] = *(const u64x2*)(&As[slot][lr][0] + kgrp * 16);
        }
        #pragma unroll
        for (int n = 0; n < 4; ++n) {
            int lc = wc * 64 + n * 16 + lrow;
            b[n] = *(const u64x2*)(&Bs[slot][lc][0] + kgrp * 16);
        }
        // ---- stage K-tile kt+2 into slot s2 (4 gloads/thread) ----
        if (stg) { STAGE_A(s2, kt + 2); STAGE_B(s2, kt + 2); }
        // ---- retire kt+1's 4 loads; kt+2's 4 stay in flight (T4) ----
        if (stg)
            asm volatile("s_waitcnt vmcnt(4)" ::: "memory");
        else
            asm volatile("s_waitcnt vmcnt(0)" ::: "memory");
        __builtin_amdgcn_s_barrier();
        asm volatile("s_waitcnt lgkmcnt(0)" ::: "memory");
        __builtin_amdgcn_s_setprio(1);
        #pragma unroll
        for (int m = 0; m < 4; ++m)
            #pragma unroll
            for (int n = 0; n < 4; ++n) {
                acc[m][n] = __builtin_amdgcn_mfma_f32_16x16x32_fp8_fp8(
                    (long)a[m][0], (long)b[n][0], acc[m][n], 0, 0, 0);
                acc[m][n] = __builtin_amdgcn_mfma_f32_16x16x32_fp8_fp8(
                    (long)a[m][1], (long)b[n][1], acc[m][n], 0, 0, 0);
            }
        __builtin_amdgcn_s_setprio(0);
        __builtin_amdgcn_s_barrier();

        slot = (slot == 2) ? 0 : slot + 1;
        s2   = (s2   == 2) ? 0 : s2 + 1;
    }

    // ---- epilogue: clip + masks + reduce (R2-verified 128x128 form) ----
    // C/D layout: col = lane&15, row = (lane>>4)*4 + reg
    float s0 = 0.f, s1 = 0.f, ps = 0.f, pc = 0.f;
    #pragma unroll
    for (int m = 0; m < 4; ++m) {
        #pragma unroll
        for (int e = 0; e < 4; ++e) {
            int li = wr * 64 + m * 16 + kgrp * 4 + e;
            int gi = rowbase + li;
            int labi = lab_r[li];
            int bi   = bia_r[li];
            #pragma unroll
            for (int n = 0; n < 4; ++n) {
                int lj = wc * 64 + n * 16 + lrow;
                int gj = colbase + lj;
                if (gi > gj) {
                    float g = acc[m][n][e];
                    g = fminf(fmaxf(g, -1.f), 1.f);
                    int bj = bia_c[lj];
                    if (bi == bj) {
                        if (bi == 0) s0 += g; else s1 += g;
                    } else if (labi == lab_c[lj] && bi < bj) {
                        ps += 1.f + g;
                        pc += 1.f;
                    }
                }
            }
        }
    }
    #pragma unroll
    for (int off = 32; off > 0; off >>= 1) {
        s0 += __shfl_down(s0, off);
        s1 += __shfl_down(s1, off);
        ps += __shfl_down(ps, off);
        pc += __shfl_down(pc, off);
    }
    if (lane == 0) {
        atomicAdd(&accbuf[0], s0);
        atomicAdd(&accbuf[1], s1);
        atomicAdd(&accbuf[2], ps);
        atomicAdd(&accbuf[3], pc);
    }
}

// ---------------------------------------------------------------------------
// Fallback (non-conforming shapes / small ws): fused f32->bf16 (R2, proven)
// ---------------------------------------------------------------------------
__global__ __launch_bounds__(256, 2)
void gram_fused_kernel(const float* __restrict__ feats,
                       const int* __restrict__ labels,
                       const int* __restrict__ biases,
                       float* __restrict__ accbuf,
                       int N, int D)
{
    __shared__ ushort_t As[128 * 64];
    __shared__ ushort_t Bs[128 * 64];
    __shared__ int lab_r[128], bia_r[128], lab_c[128], bia_c[128];

    int t = blockIdx.x;
    int r = (int)((sqrtf(8.0f * (float)t + 1.0f) - 1.0f) * 0.5f);
    while ((r + 1) * (r + 2) / 2 <= t) ++r;
    while (r * (r + 1) / 2 > t) --r;
    int c = t - r * (r + 1) / 2;
    int rowbase = r * 128, colbase = c * 128;

    int tid = threadIdx.x;
    if (tid < 128) {
        lab_r[tid] = labels[rowbase + tid];
        bia_r[tid] = biases[rowbase + tid];
    } else {
        int u = tid - 128;
        lab_c[u] = labels[colbase + u];
        bia_c[u] = biases[colbase + u];
    }

    int lane = tid & 63;
    int wid  = tid >> 6;
    int wr   = wid >> 1;
    int wc   = wid & 1;
    int lrow = lane & 15;
    int kgrp = lane >> 4;

    f32x4 acc[4][4] = {};

    for (int k0 = 0; k0 < D; k0 += 64) {
        __syncthreads();
        #pragma unroll
        for (int it = 0; it < 4; ++it) {
            int wlin = tid + it * 256;
            int row  = wlin >> 3;
            int kc   = wlin & 7;
            const float* ga = feats + (size_t)(rowbase + row) * D + k0 + kc * 8;
            const float* gb = feats + (size_t)(colbase + row) * D + k0 + kc * 8;
            f32x4 a0 = *(const f32x4*)ga;
            f32x4 a1 = *(const f32x4*)(ga + 4);
            f32x4 b0 = *(const f32x4*)gb;
            f32x4 b1 = *(const f32x4*)(gb + 4);
            bf16x8 av, bv;
            #pragma unroll
            for (int e = 0; e < 4; ++e) {
                av[e]     = f2bf(a0[e]);
                av[e + 4] = f2bf(a1[e]);
                bv[e]     = f2bf(b0[e]);
                bv[e + 4] = f2bf(b1[e]);
            }
            int boff = row * 128 + ((kc * 16) ^ ((row & 7) << 4));
            *(bf16x8*)((char*)As + boff) = av;
            *(bf16x8*)((char*)Bs + boff) = bv;
        }
        __syncthreads();

        #pragma unroll
        for (int kk = 0; kk < 2; ++kk) {
            bf16x8 a[4], bb[4];
            #pragma unroll
            for (int m = 0; m < 4; ++m) {
                int rr = wr * 64 + m * 16 + lrow;
                int off = rr * 128 + ((kk * 64 + kgrp * 16) ^ ((rr & 7) << 4));
                a[m] = *(const bf16x8*)((const char*)As + off);
            }
            #pragma unroll
            for (int n = 0; n < 4; ++n) {
                int cc = wc * 64 + n * 16 + lrow;
                int off = cc * 128 + ((kk * 64 + kgrp * 16) ^ ((cc & 7) << 4));
                bb[n] = *(const bf16x8*)((const char*)Bs + off);
            }
            #pragma unroll
            for (int m = 0; m < 4; ++m)
                #pragma unroll
                for (int n = 0; n < 4; ++n)
                    acc[m][n] = __builtin_amdgcn_mfma_f32_16x16x32_bf16(
                        a[m], bb[n], acc[m][n], 0, 0, 0);
        }
    }

    float s0 = 0.f, s1 = 0.f, ps = 0.f, pc = 0.f;
    #pragma unroll
    for (int m = 0; m < 4; ++m) {
        #pragma unroll
        for (int e = 0; e < 4; ++e) {
            int li = wr * 64 + m * 16 + kgrp * 4 + e;
            int gi = rowbase + li;
            int labi = lab_r[li];
            int bi   = bia_r[li];
            #pragma unroll
            for (int n = 0; n < 4; ++n) {
                int lj = wc * 64 + n * 16 + lrow;
                int gj = colbase + lj;
                if (gi > gj) {
                    float g = acc[m][n][e];
                    g = fminf(fmaxf(g, -1.f), 1.f);
                    int bj = bia_c[lj];
                    if (bi == bj) {
                        if (bi == 0) s0 += g; else s1 += g;
                    } else if (labi == lab_c[lj] && bi < bj) {
                        ps += 1.f + g;
                        pc += 1.f;
                    }
                }
            }
        }
    }
    #pragma unroll
    for (int off = 32; off > 0; off >>= 1) {
        s0 += __shfl_down(s0, off);
        s1 += __shfl_down(s1, off);
        ps += __shfl_down(ps, off);
        pc += __shfl_down(pc, off);
    }
    if (lane == 0) {
        atomicAdd(&accbuf[0], s0);
        atomicAdd(&accbuf[1], s1);
        atomicAdd(&accbuf[2], ps);
        atomicAdd(&accbuf[3], pc);
    }
}

// ---------------------------------------------------------------------------
// Cross-entropy + bias-class counts.  accbuf: [4]=CE sum [5]=n0 [6]=n1
// ---------------------------------------------------------------------------
__global__ __launch_bounds__(256)
void ce_count_kernel(const float* __restrict__ logits,
                     const int* __restrict__ labels,
                     const int* __restrict__ biases,
                     float* __restrict__ accbuf,
                     int N, int C)
{
    int i = blockIdx.x * blockDim.x + threadIdx.x;
    float loss = 0.f, c0 = 0.f, c1 = 0.f;
    if (i < N) {
        const float* row = logits + (size_t)i * C;
        float mx = -INFINITY;
        for (int k = 0; k < C; ++k) mx = fmaxf(mx, row[k]);
        float s = 0.f;
        for (int k = 0; k < C; ++k) s += expf(row[k] - mx);
        loss = mx + logf(s) - row[labels[i]];
        if (biases[i] == 0) c0 = 1.f; else c1 = 1.f;
    }
    #pragma unroll
    for (int off = 32; off > 0; off >>= 1) {
        loss += __shfl_down(loss, off);
        c0   += __shfl_down(c0, off);
        c1   += __shfl_down(c1, off);
    }
    if ((threadIdx.x & 63) == 0) {
        atomicAdd(&accbuf[4], loss);
        atomicAdd(&accbuf[5], c0);
        atomicAdd(&accbuf[6], c1);
    }
}

// ---------------------------------------------------------------------------
// Finalize
// ---------------------------------------------------------------------------
__global__ void finalize_kernel(const float* __restrict__ accbuf,
                                float* __restrict__ out, int N)
{
    float S0 = accbuf[0], S1 = accbuf[1], ps = accbuf[2], pc = accbuf[3];
    float ce = accbuf[4], n0 = accbuf[5], n1 = accbuf[6];
    float Mo = 0.5f * (n0 * (n0 - 1.f) + n1 * (n1 - 1.f));
    float Ro = (Mo > 0.f) ? (fabsf(S0) + fabsf(S1)) / Mo : 0.f;
    float Rp = (pc > 0.f) ? 1.f + (-0.5f * ps) / pc : 0.f;
    out[0] = ce / (float)N;
    out[1] = Ro + Rp;   // ALPHA=BETA=1
}

extern "C" void kernel_launch(void* const* d_in, const int* in_sizes, int n_in,
                              void* d_out, int out_size, void* d_ws, size_t ws_size,
                              hipStream_t stream)
{
    const float* logits = (const float*)d_in[0];
    const int*   labels = (const int*)d_in[1];
    const int*   biases = (const int*)d_in[2];
    const float* feats  = (const float*)d_in[3];

    int N = in_sizes[1];              // 4096
    int C = in_sizes[0] / N;          // 10
    int D = in_sizes[3] / N;          // 2048

    float* accbuf = (float*)d_ws;
    hipMemsetAsync(accbuf, 0, 8 * sizeof(float), stream);

    size_t need = 256 + (size_t)N * D;           // 8 MB fp8 + hdr
    if (ws_size >= need && (N & 127) == 0 && (D & 63) == 0) {
        unsigned char* fb = (unsigned char*)d_ws + 256;
        int nu = N * (D >> 4);
        convert_pair8_kernel<<<(nu + 255) / 256, 256, 0, stream>>>(feats, fb,
                                                                   N, D);
        int nt = N >> 7;              // 32
        int T  = nt * (nt + 1) / 2;   // 528 lower-tri tiles
        gram_tri8_kernel<<<T, 256, 0, stream>>>(fb, labels, biases,
                                                accbuf, N, D);
    } else {
        int nt = N / 128;
        int T  = nt * (nt + 1) / 2;
        gram_fused_kernel<<<T, 256, 0, stream>>>(feats, labels, biases, accbuf,
                                                 N, D);
    }
    ce_count_kernel<<<(N + 255) / 256, 256, 0, stream>>>(logits, labels, biases,
                                                         accbuf, N, C);
    finalize_kernel<<<1, 1, 0, stream>>>(accbuf, (float*)d_out, N);
}

// Round 18
// 134.257 us; speedup vs baseline: 1.2360x; 1.2360x over previous
//
#include <hip/hip_runtime.h>
#include <hip/hip_bf16.h>

// Types
typedef short  bf16x8 __attribute__((ext_vector_type(8)));
typedef float  f32x4  __attribute__((ext_vector_type(4)));
typedef unsigned int uint4v __attribute__((ext_vector_type(4)));
typedef unsigned long u64x2 __attribute__((ext_vector_type(2)));
typedef unsigned short ushort_t;

#define GLD_LDS16(gp, lp) __builtin_amdgcn_global_load_lds(                 \
    (const __attribute__((address_space(1))) void*)(gp),                    \
    (__attribute__((address_space(3))) void*)(lp), 16, 0, 0)

static __device__ inline short f2bf(float x) {
    unsigned u = __builtin_bit_cast(unsigned, x);
    u += 0x7fffu + ((u >> 16) & 1u);
    return (short)(u >> 16);
}

// ---------------------------------------------------------------------------
// Pre-pass: feats f32 -> fp8 e4m3, PAIR-INTERLEAVED with 2-bit UNIT SWIZZLE
// baked in (rule #21 both-sides). Unit slot u' of K-tile kt in row r holds
// pair-fragment g = u' ^ ((r>>1)&3):
//   bytes [0:8)  = fp8(feats[r][kt*64 +      g*8 .. +8))   (ks=0 frag)
//   bytes [8:16) = fp8(feats[r][kt*64 + 32 + g*8 .. +8))   (ks=1 frag)
// Read side uses u' = kgrp ^ ((row>>1)&3): a 16-lane group's 8 even rows
// spread over all 4 bank-quads (2 rows each = 2-way = free, m136), killing
// the 8-way conflict of the unswizzled layout. fb layout/staging stay linear.
// ---------------------------------------------------------------------------
__global__ __launch_bounds__(256)
void convert_pair8_kernel(const float* __restrict__ in,
                          unsigned char* __restrict__ out,
                          int N, int D)
{
    int uid = blockIdx.x * blockDim.x + threadIdx.x;   // 16B unit id
    int nw  = D >> 4;                                  // units per row
    if (uid >= N * nw) return;
    int row = uid / nw;
    int w   = uid - row * nw;
    int kt  = w >> 2;
    int g   = (w & 3) ^ ((row >> 1) & 3);              // baked swizzle
    int k0  = kt * 64 + g * 8;
    const float* s = in + (size_t)row * D + k0;
    f32x4 a0 = *(const f32x4*)s;
    f32x4 a1 = *(const f32x4*)(s + 4);
    f32x4 b0 = *(const f32x4*)(s + 32);
    f32x4 b1 = *(const f32x4*)(s + 36);
    unsigned w0 = __builtin_amdgcn_cvt_pk_fp8_f32(a0[0], a0[1], 0, 0);
    w0 = __builtin_amdgcn_cvt_pk_fp8_f32(a0[2], a0[3], w0, 1);
    unsigned w1 = __builtin_amdgcn_cvt_pk_fp8_f32(a1[0], a1[1], 0, 0);
    w1 = __builtin_amdgcn_cvt_pk_fp8_f32(a1[2], a1[3], w1, 1);
    unsigned w2 = __builtin_amdgcn_cvt_pk_fp8_f32(b0[0], b0[1], 0, 0);
    w2 = __builtin_amdgcn_cvt_pk_fp8_f32(b0[2], b0[3], w2, 1);
    unsigned w3 = __builtin_amdgcn_cvt_pk_fp8_f32(b1[0], b1[1], 0, 0);
    w3 = __builtin_amdgcn_cvt_pk_fp8_f32(b1[2], b1[3], w3, 1);
    uint4v v = {w0, w1, w2, w3};
    *(uint4v*)(out + (size_t)uid * 16) = v;
}

// ---------------------------------------------------------------------------
// Gram kernel: R16 champion structure unchanged (256x256 tile, 512 threads,
// 8 waves 2Mx4N, 32 K-tiles of 64, 2 phases/K-tile of 32 MFMA, 3-slot LDS
// rotation, counted vmcnt(4), raw barriers + lgkmcnt(0) + setprio), with
// the ds_read unit index now swizzled u = kgrp ^ ((row>>1)&3) to match the
// convert pre-pass -> 2-way (free) LDS banking instead of 8-way.
// accbuf: [0]=S0 [1]=S1 [2]=ps [3]=pc
// ---------------------------------------------------------------------------
__global__ __launch_bounds__(512, 1)
void gram_p2k64_kernel(const unsigned char* __restrict__ fb,
                       const int* __restrict__ labels,
                       const int* __restrict__ biases,
                       float* __restrict__ accbuf,
                       int N, int D)
{
    __shared__ unsigned char As[3][2][128][64];   // [slot][rowhalf][row][k] 48KB
    __shared__ unsigned char Bs[3][2][128][64];   // 48KB
    __shared__ int lab_r[256], bia_r[256], lab_c[256], bia_c[256];

    int nt = N >> 8;                   // 16
    int b  = blockIdx.x;
    int nwg = gridDim.x;
    if ((nwg & 7) == 0) b = (b & 7) * (nwg >> 3) + (b >> 3);
    int r = b / nt, c = b % nt;
    int rowbase = r * 256, colbase = c * 256;

    int tid = threadIdx.x;
    if (tid < 256) {
        lab_r[tid] = labels[rowbase + tid];
        bia_r[tid] = biases[rowbase + tid];
    } else {
        int u = tid - 256;
        lab_c[u] = labels[colbase + u];
        bia_c[u] = biases[colbase + u];
    }

    int lane = tid & 63;
    int wid  = tid >> 6;               // 8 waves
    int wr   = wid >> 2;               // 0..1  (128 rows each)
    int wc   = wid & 3;                // 0..3  (64 cols each)
    int lrow = lane & 15;
    int kgrp = lane >> 4;

    // stage one half-tile (128 rows x 64B = 8KB): 1 gload/thread, linear.
    auto STAGE_A = [&](int slot, int h, int kt) {
        int row = tid >> 2;
        int blk = tid & 3;
        const unsigned char* g =
            fb + (size_t)(rowbase + h * 128 + row) * D + kt * 64 + blk * 16;
        GLD_LDS16(g, &As[slot][h][0][0] + tid * 16);
    };
    auto STAGE_B = [&](int slot, int h, int kt) {
        int row = tid >> 2;
        int blk = tid & 3;
        const unsigned char* g =
            fb + (size_t)(colbase + h * 128 + row) * D + kt * 64 + blk * 16;
        GLD_LDS16(g, &Bs[slot][h][0][0] + tid * 16);
    };

    f32x4 acc[8][4] = {};
    int nkt = D >> 6;                  // 32 K-tiles

    // ---- prologue: kt0 -> slot0 (4 loads), kt1 -> slot1 (4); retire kt0 ----
    STAGE_A(0, 0, 0); STAGE_A(0, 1, 0); STAGE_B(0, 0, 0); STAGE_B(0, 1, 0);
    STAGE_A(1, 0, 1); STAGE_A(1, 1, 1); STAGE_B(1, 0, 1); STAGE_B(1, 1, 1);
    asm volatile("s_waitcnt vmcnt(4)" ::: "memory");
    __builtin_amdgcn_s_barrier();

    int hb  = wc >> 1;                 // B half this wave reads
    int lcb = (wc & 1) * 64;           // B local col base within half

    int slot = 0, s2 = 2;              // s2 = (kt+2)%3
    for (int kt = 0; kt < nkt; ++kt) {
        int stg = (kt + 2 < nkt);
        u64x2 breg[4];

        // ================= phase 0: m-rows 0..3 =================
        #pragma unroll
        for (int n = 0; n < 4; ++n) {
            int lc = lcb + n * 16 + lrow;
            int u  = kgrp ^ ((lc >> 1) & 3);
            breg[n] = *(const u64x2*)(&Bs[slot][hb][lc][0] + u * 16);
        }
        u64x2 a0[4];
        #pragma unroll
        for (int mm = 0; mm < 4; ++mm) {
            int lr = mm * 16 + lrow;
            int u  = kgrp ^ ((lr >> 1) & 3);
            a0[mm] = *(const u64x2*)(&As[slot][wr][lr][0] + u * 16);
        }
        if (stg) { STAGE_A(s2, 0, kt + 2); STAGE_A(s2, 1, kt + 2); }
        __builtin_amdgcn_s_barrier();
        asm volatile("s_waitcnt lgkmcnt(0)" ::: "memory");
        __builtin_amdgcn_s_setprio(1);
        #pragma unroll
        for (int mm = 0; mm < 4; ++mm)
            #pragma unroll
            for (int n = 0; n < 4; ++n) {
                acc[mm][n] = __builtin_amdgcn_mfma_f32_16x16x32_fp8_fp8(
                    (long)a0[mm][0], (long)breg[n][0], acc[mm][n], 0, 0, 0);
                acc[mm][n] = __builtin_amdgcn_mfma_f32_16x16x32_fp8_fp8(
                    (long)a0[mm][1], (long)breg[n][1], acc[mm][n], 0, 0, 0);
            }
        __builtin_amdgcn_s_setprio(0);
        __builtin_amdgcn_s_barrier();

        // ================= phase 1: m-rows 4..7 =================
        u64x2 a1[4];
        #pragma unroll
        for (int mm = 0; mm < 4; ++mm) {
            int lr = (4 + mm) * 16 + lrow;
            int u  = kgrp ^ ((lr >> 1) & 3);
            a1[mm] = *(const u64x2*)(&As[slot][wr][lr][0] + u * 16);
        }
        if (stg) { STAGE_B(s2, 0, kt + 2); STAGE_B(s2, 1, kt + 2); }
        // retire kt+1's 4 loads; kt+2's 4 stay in flight (T4)
        if (stg)
            asm volatile("s_waitcnt vmcnt(4)" ::: "memory");
        else
            asm volatile("s_waitcnt vmcnt(0)" ::: "memory");
        __builtin_amdgcn_s_barrier();
        asm volatile("s_waitcnt lgkmcnt(0)" ::: "memory");
        __builtin_amdgcn_s_setprio(1);
        #pragma unroll
        for (int mm = 0; mm < 4; ++mm)
            #pragma unroll
            for (int n = 0; n < 4; ++n) {
                acc[4 + mm][n] = __builtin_amdgcn_mfma_f32_16x16x32_fp8_fp8(
                    (long)a1[mm][0], (long)breg[n][0], acc[4 + mm][n], 0, 0, 0);
                acc[4 + mm][n] = __builtin_amdgcn_mfma_f32_16x16x32_fp8_fp8(
                    (long)a1[mm][1], (long)breg[n][1], acc[4 + mm][n], 0, 0, 0);
            }
        __builtin_amdgcn_s_setprio(0);
        __builtin_amdgcn_s_barrier();

        slot = (slot == 2) ? 0 : slot + 1;
        s2   = (s2   == 2) ? 0 : s2 + 1;
    }

    if (r < c) return;                 // strictly-upper: no i>j pairs

    // ---- epilogue: clip + masks + reduce (verified R2-R16) ----
    // C/D layout: col = lane&15, row = (lane>>4)*4 + reg
    float s0 = 0.f, s1 = 0.f, ps = 0.f, pc = 0.f;
    #pragma unroll
    for (int m = 0; m < 8; ++m) {
        #pragma unroll
        for (int e = 0; e < 4; ++e) {
            int li = wr * 128 + m * 16 + kgrp * 4 + e;
            int gi = rowbase + li;
            int labi = lab_r[li];
            int bi   = bia_r[li];
            #pragma unroll
            for (int n = 0; n < 4; ++n) {
                int lj = wc * 64 + n * 16 + lrow;
                int gj = colbase + lj;
                if (gi > gj) {
                    float g = acc[m][n][e];
                    g = fminf(fmaxf(g, -1.f), 1.f);
                    int bj = bia_c[lj];
                    if (bi == bj) {
                        if (bi == 0) s0 += g; else s1 += g;
                    } else if (labi == lab_c[lj] && bi < bj) {
                        ps += 1.f + g;
                        pc += 1.f;
                    }
                }
            }
        }
    }
    #pragma unroll
    for (int off = 32; off > 0; off >>= 1) {
        s0 += __shfl_down(s0, off);
        s1 += __shfl_down(s1, off);
        ps += __shfl_down(ps, off);
        pc += __shfl_down(pc, off);
    }
    if (lane == 0) {
        atomicAdd(&accbuf[0], s0);
        atomicAdd(&accbuf[1], s1);
        atomicAdd(&accbuf[2], ps);
        atomicAdd(&accbuf[3], pc);
    }
}

// ---------------------------------------------------------------------------
// Fallback (non-conforming shapes / small ws): fused f32->bf16 (R2, proven)
// ---------------------------------------------------------------------------
__global__ __launch_bounds__(256, 2)
void gram_fused_kernel(const float* __restrict__ feats,
                       const int* __restrict__ labels,
                       const int* __restrict__ biases,
                       float* __restrict__ accbuf,
                       int N, int D)
{
    __shared__ ushort_t As[128 * 64];
    __shared__ ushort_t Bs[128 * 64];
    __shared__ int lab_r[128], bia_r[128], lab_c[128], bia_c[128];

    int t = blockIdx.x;
    int r = (int)((sqrtf(8.0f * (float)t + 1.0f) - 1.0f) * 0.5f);
    while ((r + 1) * (r + 2) / 2 <= t) ++r;
    while (r * (r + 1) / 2 > t) --r;
    int c = t - r * (r + 1) / 2;
    int rowbase = r * 128, colbase = c * 128;

    int tid = threadIdx.x;
    if (tid < 128) {
        lab_r[tid] = labels[rowbase + tid];
        bia_r[tid] = biases[rowbase + tid];
    } else {
        int u = tid - 128;
        lab_c[u] = labels[colbase + u];
        bia_c[u] = biases[colbase + u];
    }

    int lane = tid & 63;
    int wid  = tid >> 6;
    int wr   = wid >> 1;
    int wc   = wid & 1;
    int lrow = lane & 15;
    int kgrp = lane >> 4;

    f32x4 acc[4][4] = {};

    for (int k0 = 0; k0 < D; k0 += 64) {
        __syncthreads();
        #pragma unroll
        for (int it = 0; it < 4; ++it) {
            int wlin = tid + it * 256;
            int row  = wlin >> 3;
            int kc   = wlin & 7;
            const float* ga = feats + (size_t)(rowbase + row) * D + k0 + kc * 8;
            const float* gb = feats + (size_t)(colbase + row) * D + k0 + kc * 8;
            f32x4 a0 = *(const f32x4*)ga;
            f32x4 a1 = *(const f32x4*)(ga + 4);
            f32x4 b0 = *(const f32x4*)gb;
            f32x4 b1 = *(const f32x4*)(gb + 4);
            bf16x8 av, bv;
            #pragma unroll
            for (int e = 0; e < 4; ++e) {
                av[e]     = f2bf(a0[e]);
                av[e + 4] = f2bf(a1[e]);
                bv[e]     = f2bf(b0[e]);
                bv[e + 4] = f2bf(b1[e]);
            }
            int boff = row * 128 + ((kc * 16) ^ ((row & 7) << 4));
            *(bf16x8*)((char*)As + boff) = av;
            *(bf16x8*)((char*)Bs + boff) = bv;
        }
        __syncthreads();

        #pragma unroll
        for (int kk = 0; kk < 2; ++kk) {
            bf16x8 a[4], bb[4];
            #pragma unroll
            for (int m = 0; m < 4; ++m) {
                int rr = wr * 64 + m * 16 + lrow;
                int off = rr * 128 + ((kk * 64 + kgrp * 16) ^ ((rr & 7) << 4));
                a[m] = *(const bf16x8*)((const char*)As + off);
            }
            #pragma unroll
            for (int n = 0; n < 4; ++n) {
                int cc = wc * 64 + n * 16 + lrow;
                int off = cc * 128 + ((kk * 64 + kgrp * 16) ^ ((cc & 7) << 4));
                bb[n] = *(const bf16x8*)((const char*)Bs + off);
            }
            #pragma unroll
            for (int m = 0; m < 4; ++m)
                #pragma unroll
                for (int n = 0; n < 4; ++n)
                    acc[m][n] = __builtin_amdgcn_mfma_f32_16x16x32_bf16(
                        a[m], bb[n], acc[m][n], 0, 0, 0);
        }
    }

    float s0 = 0.f, s1 = 0.f, ps = 0.f, pc = 0.f;
    #pragma unroll
    for (int m = 0; m < 4; ++m) {
        #pragma unroll
        for (int e = 0; e < 4; ++e) {
            int li = wr * 64 + m * 16 + kgrp * 4 + e;
            int gi = rowbase + li;
            int labi = lab_r[li];
            int bi   = bia_r[li];
            #pragma unroll
            for (int n = 0; n < 4; ++n) {
                int lj = wc * 64 + n * 16 + lrow;
                int gj = colbase + lj;
                if (gi > gj) {
                    float g = acc[m][n][e];
                    g = fminf(fmaxf(g, -1.f), 1.f);
                    int bj = bia_c[lj];
                    if (bi == bj) {
                        if (bi == 0) s0 += g; else s1 += g;
                    } else if (labi == lab_c[lj] && bi < bj) {
                        ps += 1.f + g;
                        pc += 1.f;
                    }
                }
            }
        }
    }
    #pragma unroll
    for (int off = 32; off > 0; off >>= 1) {
        s0 += __shfl_down(s0, off);
        s1 += __shfl_down(s1, off);
        ps += __shfl_down(ps, off);
        pc += __shfl_down(pc, off);
    }
    if (lane == 0) {
        atomicAdd(&accbuf[0], s0);
        atomicAdd(&accbuf[1], s1);
        atomicAdd(&accbuf[2], ps);
        atomicAdd(&accbuf[3], pc);
    }
}

// ---------------------------------------------------------------------------
// Cross-entropy + bias-class counts.  accbuf: [4]=CE sum [5]=n0 [6]=n1
// ---------------------------------------------------------------------------
__global__ __launch_bounds__(256)
void ce_count_kernel(const float* __restrict__ logits,
                     const int* __restrict__ labels,
                     const int* __restrict__ biases,
                     float* __restrict__ accbuf,
                     int N, int C)
{
    int i = blockIdx.x * blockDim.x + threadIdx.x;
    float loss = 0.f, c0 = 0.f, c1 = 0.f;
    if (i < N) {
        const float* row = logits + (size_t)i * C;
        float mx = -INFINITY;
        for (int k = 0; k < C; ++k) mx = fmaxf(mx, row[k]);
        float s = 0.f;
        for (int k = 0; k < C; ++k) s += expf(row[k] - mx);
        loss = mx + logf(s) - row[labels[i]];
        if (biases[i] == 0) c0 = 1.f; else c1 = 1.f;
    }
    #pragma unroll
    for (int off = 32; off > 0; off >>= 1) {
        loss += __shfl_down(loss, off);
        c0   += __shfl_down(c0, off);
        c1   += __shfl_down(c1, off);
    }
    if ((threadIdx.x & 63) == 0) {
        atomicAdd(&accbuf[4], loss);
        atomicAdd(&accbuf[5], c0);
        atomicAdd(&accbuf[6], c1);
    }
}

// ---------------------------------------------------------------------------
// Finalize
// ---------------------------------------------------------------------------
__global__ void finalize_kernel(const float* __restrict__ accbuf,
                                float* __restrict__ out, int N)
{
    float S0 = accbuf[0], S1 = accbuf[1], ps = accbuf[2], pc = accbuf[3];
    float ce = accbuf[4], n0 = accbuf[5], n1 = accbuf[6];
    float Mo = 0.5f * (n0 * (n0 - 1.f) + n1 * (n1 - 1.f));
    float Ro = (Mo > 0.f) ? (fabsf(S0) + fabsf(S1)) / Mo : 0.f;
    float Rp = (pc > 0.f) ? 1.f + (-0.5f * ps) / pc : 0.f;
    out[0] = ce / (float)N;
    out[1] = Ro + Rp;   // ALPHA=BETA=1
}

extern "C" void kernel_launch(void* const* d_in, const int* in_sizes, int n_in,
                              void* d_out, int out_size, void* d_ws, size_t ws_size,
                              hipStream_t stream)
{
    const float* logits = (const float*)d_in[0];
    const int*   labels = (const int*)d_in[1];
    const int*   biases = (const int*)d_in[2];
    const float* feats  = (const float*)d_in[3];

    int N = in_sizes[1];              // 4096
    int C = in_sizes[0] / N;          // 10
    int D = in_sizes[3] / N;          // 2048

    float* accbuf = (float*)d_ws;
    hipMemsetAsync(accbuf, 0, 8 * sizeof(float), stream);

    size_t need = 256 + (size_t)N * D;           // 8 MB fp8 + hdr
    if (ws_size >= need && (N & 255) == 0 && (D & 63) == 0) {
        unsigned char* fb = (unsigned char*)d_ws + 256;
        int nu = N * (D >> 4);
        convert_pair8_kernel<<<(nu + 255) / 256, 256, 0, stream>>>(feats, fb,
                                                                   N, D);
        int nt = N >> 8;              // 16
        gram_p2k64_kernel<<<nt * nt, 512, 0, stream>>>(fb, labels, biases,
                                                       accbuf, N, D);
    } else {
        int nt = N / 128;
        int T  = nt * (nt + 1) / 2;
        gram_fused_kernel<<<T, 256, 0, stream>>>(feats, labels, biases, accbuf,
                                                 N, D);
    }
    ce_count_kernel<<<(N + 255) / 256, 256, 0, stream>>>(logits, labels, biases,
                                                         accbuf, N, C);
    finalize_kernel<<<1, 1, 0, stream>>>(accbuf, (float*)d_out, N);
}